// Round 4
// baseline (630.741 us; speedup 1.0000x reference)
//
#include <hip/hip_runtime.h>
#include <hip/hip_bf16.h>

#define SEQ 262144   // d*h*w = 16*128*128
#define PAD 260      // ushort elements per LDS row; 520B rows -> 8B aligned, bank-spread

__device__ __forceinline__ float bflo(unsigned u) { return __uint_as_float(u << 16); }
__device__ __forceinline__ float bfhi(unsigned u) { return __uint_as_float(u & 0xffff0000u); }
__device__ __forceinline__ unsigned short f2bf(float f) {
    unsigned b = __float_as_uint(f);
    b += 0x7fffu + ((b >> 16) & 1u);   // round-to-nearest-even
    return (unsigned short)(b >> 16);
}

// Kernel 1: k = exp(Wk@x + bk) (unnormalized), v = Wv@x + bv
// accumulate ctx[n][h][kc][vc] = sum_s ek*v  and z[n][ch] = sum_s ek  via atomics.
__global__ __launch_bounds__(256) void nl_k1(
    const float* __restrict__ x,
    const float* __restrict__ Wk, const float* __restrict__ bk,
    const float* __restrict__ Wv, const float* __restrict__ bv,
    float* __restrict__ ctx_g, float* __restrict__ z_g)
{
    __shared__ unsigned short EKs[32 * PAD];
    __shared__ unsigned short Vs [32 * PAD];

    const int tid   = threadIdx.x;
    const int b     = blockIdx.x;      // 512 blocks: 256 per batch n
    const int n     = b >> 8;
    const int chunk = b & 255;
    const float* xn = x + (size_t)n * 64 * SEQ;

    // each thread owns 2 ctx entries: e0 = tid (head 0), e1 = 256+tid (head 1)
    const int rk0 = tid >> 4, rv0 = tid & 15;
    const int rk1 = rk0 + 16, rv1 = rv0 + 16;
    float acc0 = 0.f, acc1 = 0.f, zacc = 0.f;
    const int zrow = tid >> 3;             // 32 rows x 8 segments
    const int zseg = (tid & 7) * 32;

    for (int tile = 0; tile < 4; ++tile) {
        const int s = chunk * 1024 + tile * 256 + tid;

        float xr[64];
        #pragma unroll
        for (int c = 0; c < 64; ++c) xr[c] = xn[(size_t)c * SEQ + s];

        float ek[32], vv[32];
        #pragma unroll
        for (int o = 0; o < 32; ++o) {
            const float4* wk4 = reinterpret_cast<const float4*>(Wk + o * 64);
            const float4* wv4 = reinterpret_cast<const float4*>(Wv + o * 64);
            float ak = bk[o], av = bv[o];
            #pragma unroll
            for (int c4 = 0; c4 < 16; ++c4) {
                const float4 wa = wk4[c4];
                const float4 wb = wv4[c4];
                ak = fmaf(wa.x, xr[c4*4+0], ak); av = fmaf(wb.x, xr[c4*4+0], av);
                ak = fmaf(wa.y, xr[c4*4+1], ak); av = fmaf(wb.y, xr[c4*4+1], av);
                ak = fmaf(wa.z, xr[c4*4+2], ak); av = fmaf(wb.z, xr[c4*4+2], av);
                ak = fmaf(wa.w, xr[c4*4+3], ak); av = fmaf(wb.w, xr[c4*4+3], av);
            }
            ek[o] = __expf(ak);   // no max-sub: k_lin ~ N(0,1), exp <= ~150, fp32-safe
            vv[o] = av;
        }

        __syncthreads();   // protect LDS vs previous tile's readers
        #pragma unroll
        for (int o = 0; o < 32; ++o) {
            EKs[o * PAD + tid] = f2bf(ek[o]);
            Vs [o * PAD + tid] = f2bf(vv[o]);
        }
        __syncthreads();

        // ctx partial: acc += sum_t EK[row_k][t] * V[row_v][t]  (broadcast LDS reads)
        for (int t = 0; t < 256; t += 4) {
            const uint2 ka = *reinterpret_cast<const uint2*>(&EKs[rk0 * PAD + t]);
            const uint2 va = *reinterpret_cast<const uint2*>(&Vs [rv0 * PAD + t]);
            const uint2 kb = *reinterpret_cast<const uint2*>(&EKs[rk1 * PAD + t]);
            const uint2 vb = *reinterpret_cast<const uint2*>(&Vs [rv1 * PAD + t]);
            acc0 = fmaf(bflo(ka.x), bflo(va.x), acc0);
            acc0 = fmaf(bfhi(ka.x), bfhi(va.x), acc0);
            acc0 = fmaf(bflo(ka.y), bflo(va.y), acc0);
            acc0 = fmaf(bfhi(ka.y), bfhi(va.y), acc0);
            acc1 = fmaf(bflo(kb.x), bflo(vb.x), acc1);
            acc1 = fmaf(bfhi(kb.x), bfhi(vb.x), acc1);
            acc1 = fmaf(bflo(kb.y), bflo(vb.y), acc1);
            acc1 = fmaf(bfhi(kb.y), bfhi(vb.y), acc1);
        }
        // z partial from the SAME staged bf16 ek (numerator/denominator consistent)
        for (int t = zseg; t < zseg + 32; t += 4) {
            const uint2 p = *reinterpret_cast<const uint2*>(&EKs[zrow * PAD + t]);
            zacc += bflo(p.x) + bfhi(p.x) + bflo(p.y) + bfhi(p.y);
        }
    }

    atomicAdd(&ctx_g[n * 512 + tid],       acc0);
    atomicAdd(&ctx_g[n * 512 + 256 + tid], acc1);

    // reduce z over the 8 segments (8 consecutive lanes per row)
    zacc += __shfl_xor(zacc, 1, 8);
    zacc += __shfl_xor(zacc, 2, 8);
    zacc += __shfl_xor(zacc, 4, 8);
    if ((tid & 7) == 0) atomicAdd(&z_g[n * 32 + zrow], zacc);
}

// Kernel 2: per voxel: q proj + head softmax, att = ctx_norm^T q, out = Wr@att + br + x
__global__ __launch_bounds__(256) void nl_k2(
    const float* __restrict__ x,
    const float* __restrict__ Wq, const float* __restrict__ bq,
    const float* __restrict__ Wr, const float* __restrict__ br,
    const float* __restrict__ ctx_g, const float* __restrict__ z_g,
    float* __restrict__ out)
{
    __shared__ float ctxn[512];
    const int tid = threadIdx.x;
    const int b   = blockIdx.x;       // 2048 blocks: 1024 per batch n
    const int n   = b >> 10;
    const int s   = (b & 1023) * 256 + tid;

    // normalized context for this n: ctxn[h*256 + kc*16 + vc] = ctx / z[kc-row]
    ctxn[tid]       = ctx_g[n * 512 + tid]       / z_g[n * 32 + (tid >> 4)];
    ctxn[tid + 256] = ctx_g[n * 512 + 256 + tid] / z_g[n * 32 + 16 + (tid >> 4)];
    __syncthreads();

    const float* xn = x + (size_t)n * 64 * SEQ;
    float xr[64];
    #pragma unroll
    for (int c = 0; c < 64; ++c) xr[c] = xn[(size_t)c * SEQ + s];

    float ql[32];
    #pragma unroll
    for (int o = 0; o < 32; ++o) {
        const float4* w4 = reinterpret_cast<const float4*>(Wq + o * 64);
        float a = bq[o];
        #pragma unroll
        for (int c4 = 0; c4 < 16; ++c4) {
            const float4 w = w4[c4];
            a = fmaf(w.x, xr[c4*4+0], a);
            a = fmaf(w.y, xr[c4*4+1], a);
            a = fmaf(w.z, xr[c4*4+2], a);
            a = fmaf(w.w, xr[c4*4+3], a);
        }
        ql[o] = a;
    }

    float att[32];
    #pragma unroll
    for (int h = 0; h < 2; ++h) {
        float m = ql[h*16];
        #pragma unroll
        for (int j = 1; j < 16; ++j) m = fmaxf(m, ql[h*16 + j]);
        float eq[16]; float se = 0.f;
        #pragma unroll
        for (int j = 0; j < 16; ++j) { eq[j] = __expf(ql[h*16 + j] - m); se += eq[j]; }
        #pragma unroll
        for (int vc = 0; vc < 16; ++vc) att[h*16 + vc] = 0.f;
        #pragma unroll
        for (int kc = 0; kc < 16; ++kc) {
            const float e = eq[kc];
            #pragma unroll
            for (int vc = 0; vc < 16; ++vc)
                att[h*16 + vc] = fmaf(e, ctxn[h*256 + kc*16 + vc], att[h*16 + vc]);
        }
        const float inv = 1.f / se;
        #pragma unroll
        for (int vc = 0; vc < 16; ++vc) att[h*16 + vc] *= inv;
    }

    float* outn = out + (size_t)n * 64 * SEQ;
    #pragma unroll
    for (int c = 0; c < 64; ++c) {
        const float4* w4 = reinterpret_cast<const float4*>(Wr + c * 32);
        float a = br[c] + xr[c];
        #pragma unroll
        for (int j4 = 0; j4 < 8; ++j4) {
            const float4 w = w4[j4];
            a = fmaf(w.x, att[j4*4+0], a);
            a = fmaf(w.y, att[j4*4+1], a);
            a = fmaf(w.z, att[j4*4+2], a);
            a = fmaf(w.w, att[j4*4+3], a);
        }
        outn[(size_t)c * SEQ + s] = a;
    }
}

extern "C" void kernel_launch(void* const* d_in, const int* in_sizes, int n_in,
                              void* d_out, int out_size, void* d_ws, size_t ws_size,
                              hipStream_t stream) {
    const float* x  = (const float*)d_in[0];
    const float* Wk = (const float*)d_in[1];
    const float* bk = (const float*)d_in[2];
    const float* Wq = (const float*)d_in[3];
    const float* bq = (const float*)d_in[4];
    const float* Wv = (const float*)d_in[5];
    const float* bv = (const float*)d_in[6];
    const float* Wr = (const float*)d_in[7];
    const float* br = (const float*)d_in[8];
    float* out   = (float*)d_out;
    float* ctx_g = (float*)d_ws;          // 2*512 floats
    float* z_g   = ctx_g + 1024;          // 2*32 floats

    hipMemsetAsync(d_ws, 0, 1088 * sizeof(float), stream);  // ws is re-poisoned 0xAA
    nl_k1<<<dim3(512),  dim3(256), 0, stream>>>(x, Wk, bk, Wv, bv, ctx_g, z_g);
    nl_k2<<<dim3(2048), dim3(256), 0, stream>>>(x, Wq, bq, Wr, br, ctx_g, z_g, out);
}

// Round 5
// 518.604 us; speedup vs baseline: 1.2162x; 1.2162x over previous
//
#include <hip/hip_runtime.h>
#include <hip/hip_bf16.h>

#define SEQ 262144   // d*h*w = 16*128*128
#define PAD 260      // ushort elements per LDS row; 520B rows -> 8B aligned, bank-spread

__device__ __forceinline__ float bflo(unsigned u) { return __uint_as_float(u << 16); }
__device__ __forceinline__ float bfhi(unsigned u) { return __uint_as_float(u & 0xffff0000u); }
__device__ __forceinline__ unsigned short f2bf(float f) {
    unsigned b = __float_as_uint(f);
    b += 0x7fffu + ((b >> 16) & 1u);   // round-to-nearest-even
    return (unsigned short)(b >> 16);
}

// Kernel 1: k = exp(Wk@x + bk) (unnormalized), v = Wv@x + bv
// accumulate ctx[n][h][kc][vc] = sum_s ek*v and z[n][ch] = sum_s ek via atomics.
// Regrid vs r4: 2048 blocks x 1 tile (was 512 x 4) -> 8 blocks/CU available;
// VGPR(148) caps at 3 waves/SIMD so occupancy ~37% (was 11.8%).
__global__ __launch_bounds__(256) void nl_k1(
    const float* __restrict__ x,
    const float* __restrict__ Wk, const float* __restrict__ bk,
    const float* __restrict__ Wv, const float* __restrict__ bv,
    float* __restrict__ ctx_g, float* __restrict__ z_g)
{
    __shared__ unsigned short EKs[32 * PAD];
    __shared__ unsigned short Vs [32 * PAD];

    const int tid   = threadIdx.x;
    const int b     = blockIdx.x;      // 2048 blocks: 1024 per batch n
    const int n     = b >> 10;
    const int chunk = b & 1023;
    const int s     = chunk * 256 + tid;
    const float* xn = x + (size_t)n * 64 * SEQ;

    float xr[64];
    #pragma unroll
    for (int c = 0; c < 64; ++c) xr[c] = xn[(size_t)c * SEQ + s];

    float ek[32], vv[32];
    #pragma unroll
    for (int o = 0; o < 32; ++o) {
        const float4* wk4 = reinterpret_cast<const float4*>(Wk + o * 64);
        const float4* wv4 = reinterpret_cast<const float4*>(Wv + o * 64);
        float ak = bk[o], av = bv[o];
        #pragma unroll
        for (int c4 = 0; c4 < 16; ++c4) {
            const float4 wa = wk4[c4];
            const float4 wb = wv4[c4];
            ak = fmaf(wa.x, xr[c4*4+0], ak); av = fmaf(wb.x, xr[c4*4+0], av);
            ak = fmaf(wa.y, xr[c4*4+1], ak); av = fmaf(wb.y, xr[c4*4+1], av);
            ak = fmaf(wa.z, xr[c4*4+2], ak); av = fmaf(wb.z, xr[c4*4+2], av);
            ak = fmaf(wa.w, xr[c4*4+3], ak); av = fmaf(wb.w, xr[c4*4+3], av);
        }
        ek[o] = __expf(ak);   // no max-sub: k_lin ~ N(0,1), fp32-safe
        vv[o] = av;
    }

    #pragma unroll
    for (int o = 0; o < 32; ++o) {
        EKs[o * PAD + tid] = f2bf(ek[o]);
        Vs [o * PAD + tid] = f2bf(vv[o]);
    }
    __syncthreads();

    // each thread owns 2 ctx entries: e0 = tid (head 0), e1 = 256+tid (head 1)
    const int rk0 = tid >> 4, rv0 = tid & 15;
    const int rk1 = rk0 + 16, rv1 = rv0 + 16;
    float acc0 = 0.f, acc1 = 0.f;

    for (int t = 0; t < 256; t += 4) {
        const uint2 ka = *reinterpret_cast<const uint2*>(&EKs[rk0 * PAD + t]);
        const uint2 va = *reinterpret_cast<const uint2*>(&Vs [rv0 * PAD + t]);
        const uint2 kb = *reinterpret_cast<const uint2*>(&EKs[rk1 * PAD + t]);
        const uint2 vb = *reinterpret_cast<const uint2*>(&Vs [rv1 * PAD + t]);
        acc0 = fmaf(bflo(ka.x), bflo(va.x), acc0);
        acc0 = fmaf(bfhi(ka.x), bfhi(va.x), acc0);
        acc0 = fmaf(bflo(ka.y), bflo(va.y), acc0);
        acc0 = fmaf(bfhi(ka.y), bfhi(va.y), acc0);
        acc1 = fmaf(bflo(kb.x), bflo(vb.x), acc1);
        acc1 = fmaf(bfhi(kb.x), bfhi(vb.x), acc1);
        acc1 = fmaf(bflo(kb.y), bflo(vb.y), acc1);
        acc1 = fmaf(bfhi(kb.y), bfhi(vb.y), acc1);
    }
    // z partial from the SAME staged bf16 ek (numerator/denominator consistent)
    const int zrow = tid >> 3;             // 32 rows x 8 segments of 32
    const int zseg = (tid & 7) * 32;
    float zacc = 0.f;
    for (int t = zseg; t < zseg + 32; t += 4) {
        const uint2 p = *reinterpret_cast<const uint2*>(&EKs[zrow * PAD + t]);
        zacc += bflo(p.x) + bfhi(p.x) + bflo(p.y) + bfhi(p.y);
    }

    atomicAdd(&ctx_g[n * 512 + tid],       acc0);
    atomicAdd(&ctx_g[n * 512 + 256 + tid], acc1);

    zacc += __shfl_xor(zacc, 1, 8);
    zacc += __shfl_xor(zacc, 2, 8);
    zacc += __shfl_xor(zacc, 4, 8);
    if ((tid & 7) == 0) atomicAdd(&z_g[n * 32 + zrow], zacc);
}

// Kernel 1b: tiny normalize pass: ctxn[n][e] = ctx[n][e] / z[n][e>>4]
__global__ __launch_bounds__(512) void nl_k1b(
    const float* __restrict__ ctx_g, const float* __restrict__ z_g,
    float* __restrict__ ctxn)
{
    const int n = blockIdx.x;          // 2 blocks
    const int e = threadIdx.x;         // 512 entries: h*256 + kc*16 + vc
    ctxn[n * 512 + e] = ctx_g[n * 512 + e] / z_g[n * 32 + (e >> 4)];
}

// Kernel 2: per voxel: q proj + head softmax, att = ctxn^T q, out = Wr@att + br + x
// vs r4: ctxn read via block-uniform addresses (compiler -> s_load, scalar cache)
// instead of 512 broadcast ds_reads/thread; no LDS, no per-block divides.
__global__ __launch_bounds__(256) void nl_k2(
    const float* __restrict__ x,
    const float* __restrict__ Wq, const float* __restrict__ bq,
    const float* __restrict__ Wr, const float* __restrict__ br,
    const float* __restrict__ ctxn, float* __restrict__ out)
{
    const int tid = threadIdx.x;
    const int b   = blockIdx.x;       // 2048 blocks: 1024 per batch n
    const int n   = b >> 10;
    const int s   = (b & 1023) * 256 + tid;

    const float* xn = x + (size_t)n * 64 * SEQ;
    float xr[64];
    #pragma unroll
    for (int c = 0; c < 64; ++c) xr[c] = xn[(size_t)c * SEQ + s];

    float ql[32];
    #pragma unroll
    for (int o = 0; o < 32; ++o) {
        const float4* w4 = reinterpret_cast<const float4*>(Wq + o * 64);
        float a = bq[o];
        #pragma unroll
        for (int c4 = 0; c4 < 16; ++c4) {
            const float4 w = w4[c4];
            a = fmaf(w.x, xr[c4*4+0], a);
            a = fmaf(w.y, xr[c4*4+1], a);
            a = fmaf(w.z, xr[c4*4+2], a);
            a = fmaf(w.w, xr[c4*4+3], a);
        }
        ql[o] = a;
    }

    const float* ctxb = ctxn + n * 512;
    float att[32];
    #pragma unroll
    for (int h = 0; h < 2; ++h) {
        float m = ql[h*16];
        #pragma unroll
        for (int j = 1; j < 16; ++j) m = fmaxf(m, ql[h*16 + j]);
        float eq[16]; float se = 0.f;
        #pragma unroll
        for (int j = 0; j < 16; ++j) { eq[j] = __expf(ql[h*16 + j] - m); se += eq[j]; }
        #pragma unroll
        for (int vc = 0; vc < 16; ++vc) att[h*16 + vc] = 0.f;
        #pragma unroll
        for (int kc = 0; kc < 16; ++kc) {
            const float e = eq[kc];
            const float4* cr = reinterpret_cast<const float4*>(ctxb + h*256 + kc*16);
            #pragma unroll
            for (int v4 = 0; v4 < 4; ++v4) {
                const float4 cv = cr[v4];   // block-uniform -> scalar load
                att[h*16 + v4*4+0] = fmaf(e, cv.x, att[h*16 + v4*4+0]);
                att[h*16 + v4*4+1] = fmaf(e, cv.y, att[h*16 + v4*4+1]);
                att[h*16 + v4*4+2] = fmaf(e, cv.z, att[h*16 + v4*4+2]);
                att[h*16 + v4*4+3] = fmaf(e, cv.w, att[h*16 + v4*4+3]);
            }
        }
        const float inv = 1.f / se;
        #pragma unroll
        for (int vc = 0; vc < 16; ++vc) att[h*16 + vc] *= inv;
    }

    float* outn = out + (size_t)n * 64 * SEQ;
    #pragma unroll
    for (int c = 0; c < 64; ++c) {
        const float4* w4 = reinterpret_cast<const float4*>(Wr + c * 32);
        float a = br[c] + xr[c];
        #pragma unroll
        for (int j4 = 0; j4 < 8; ++j4) {
            const float4 w = w4[j4];
            a = fmaf(w.x, att[j4*4+0], a);
            a = fmaf(w.y, att[j4*4+1], a);
            a = fmaf(w.z, att[j4*4+2], a);
            a = fmaf(w.w, att[j4*4+3], a);
        }
        outn[(size_t)c * SEQ + s] = a;
    }
}

extern "C" void kernel_launch(void* const* d_in, const int* in_sizes, int n_in,
                              void* d_out, int out_size, void* d_ws, size_t ws_size,
                              hipStream_t stream) {
    const float* x  = (const float*)d_in[0];
    const float* Wk = (const float*)d_in[1];
    const float* bk = (const float*)d_in[2];
    const float* Wq = (const float*)d_in[3];
    const float* bq = (const float*)d_in[4];
    const float* Wv = (const float*)d_in[5];
    const float* bv = (const float*)d_in[6];
    const float* Wr = (const float*)d_in[7];
    const float* br = (const float*)d_in[8];
    float* out   = (float*)d_out;
    float* ctx_g = (float*)d_ws;          // 2*512 floats
    float* z_g   = ctx_g + 1024;          // 2*32 floats
    float* ctxn  = z_g + 64;              // 2*512 floats (written by k1b)

    hipMemsetAsync(d_ws, 0, 1088 * sizeof(float), stream);  // zero ctx_g + z_g
    nl_k1 <<<dim3(2048), dim3(256), 0, stream>>>(x, Wk, bk, Wv, bv, ctx_g, z_g);
    nl_k1b<<<dim3(2),    dim3(512), 0, stream>>>(ctx_g, z_g, ctxn);
    nl_k2 <<<dim3(2048), dim3(256), 0, stream>>>(x, Wq, bq, Wr, br, ctxn, out);
}